// Round 9
// baseline (332.873 us; speedup 1.0000x reference)
//
#include <hip/hip_runtime.h>

#define BDIM 4
#define LDIM 4096
#define DDIM 1024
#define KTAPS 128
#define LCHUNK 128

typedef __attribute__((ext_vector_type(8))) _Float16 f16x8;
typedef __attribute__((ext_vector_type(16))) float f32x16;

// ---------------------------------------------------------------------------
// fp16 helpers
// ---------------------------------------------------------------------------
__device__ __forceinline__ float f16_to_f(ushort h) {
    return (float)__builtin_bit_cast(_Float16, h);
}
__device__ __forceinline__ ushort f_to_f16(float f) {
    return __builtin_bit_cast(ushort, (_Float16)f);  // v_cvt_f16_f32, RNE
}

__device__ __forceinline__ void load_lds16(const ushort* g, ushort* l) {
    __builtin_amdgcn_global_load_lds(
        (const __attribute__((address_space(1))) void*)g,
        (__attribute__((address_space(3))) void*)l, 16, 0, 0);
}

// granule swizzle for LDS row r (4 octets of 16B per 64B row); period-16 in r
#define NSWZ(r) ((((r) & 3) ^ (((r) >> 2) & 3)))

// ---------------------------------------------------------------------------
// fused fp32 -> fp16 convert for all three inputs (one launch)
// ---------------------------------------------------------------------------
#define NX4 (BDIM * LDIM * DDIM / 4)        // 4194304
#define NQ4 (3 * DDIM * DDIM / 4)           // 786432
#define NO4 (DDIM * DDIM / 4)               // 262144
__global__ __launch_bounds__(256) void to_f16_all(const float* __restrict__ x,
                                                  const float* __restrict__ wq,
                                                  const float* __restrict__ wo,
                                                  ushort* __restrict__ xh,
                                                  ushort* __restrict__ wqh,
                                                  ushort* __restrict__ woh) {
    const int ntot = NX4 + NQ4 + NO4;
    for (int i = blockIdx.x * 256 + threadIdx.x; i < ntot; i += gridDim.x * 256) {
        const float* src;
        ushort* dst;
        int j = i;
        if (j < NX4) {
            src = x; dst = xh;
        } else if (j < NX4 + NQ4) {
            j -= NX4; src = wq; dst = wqh;
        } else {
            j -= NX4 + NQ4; src = wo; dst = woh;
        }
        const float4 v = *(const float4*)&src[(size_t)j * 4];
        ushort4 h;
        h.x = f_to_f16(v.x);
        h.y = f_to_f16(v.y);
        h.z = f_to_f16(v.z);
        h.w = f_to_f16(v.w);
        *(ushort4*)&dst[(size_t)j * 4] = h;
    }
}

// ---------------------------------------------------------------------------
// fp16 NT GEMM: 128x128 tile, BK=32, 4 waves, 32x32x16 MFMA (r8 mapping),
// ROUND-9 CHANGE: 2-phase prefetch double-buffer (T3-minimum). Tile t+1's
// global_load_lds are issued BEFORE tile t's ds_read+MFMA, so the implicit
// vmcnt(0) at the end-of-iter __syncthreads() lands after a full compute
// window — the ~500cyc/iter staging latency that r4-r8 exposed between
// back-to-back barriers is now hidden. One barrier per iter (was two).
// Hazards: STAGE always targets the opposite buffer of all in-flight
// ds_reads; each buffer's reads are register-consumed (compiler lgkm waits)
// before the barrier preceding its overwrite.
// A/B frag map: lane l -> row/col = l&31, k-octet = l>>5;
// C/D map (m74/m101): col = lane&31, row = (q&3)+8*(q>>2)+4*(lane>>5).
// OBF=1 -> f16 C, OBF=0 -> f32 C. XCD-aware tile swizzle.
// ---------------------------------------------------------------------------
template <int OBF>
__global__ __launch_bounds__(256) void gemm_f16(const ushort* __restrict__ A,
                                                const ushort* __restrict__ B,
                                                void* __restrict__ Cp, int ldc, int Kc) {
    __shared__ ushort As[2][128 * 32];
    __shared__ ushort Bs[2][128 * 32];

    const int tid = threadIdx.x;

    // bijective XCD swizzle (nwg % 8 == 0 for all our grids)
    const int gx = gridDim.x;
    const int nwg = gx * gridDim.y;
    const int orig = blockIdx.y * gx + blockIdx.x;
    const int q8 = nwg >> 3;
    const int tile = (orig & 7) * q8 + (orig >> 3);
    const int m0 = (tile / gx) * 128;
    const int n0 = (tile % gx) * 128;

    // staging: thread t -> LDS rows t>>2 and t>>2 + 64, octet t&3; inverse-swizzled src
    const int ra = tid >> 2;
    const int ga = tid & 3;
    const int gs = (ga ^ NSWZ(ra)) * 8;

    const ushort* srcA0 = A + (size_t)(m0 + ra) * Kc + gs;
    const ushort* srcA1 = A + (size_t)(m0 + 64 + ra) * Kc + gs;
    const ushort* srcB0 = B + (size_t)(n0 + ra) * Kc + gs;
    const ushort* srcB1 = B + (size_t)(n0 + 64 + ra) * Kc + gs;

    const int lane = tid & 63;
    const int w = tid >> 6;
    const int wr = w >> 1, wc = w & 1;  // wave 64x64 sub-tile
    const int l31 = lane & 31;
    const int hi = lane >> 5;           // k-octet half (A/B), +4 row offset (C/D)
    const int nsw = NSWZ(l31 & 15);
    const int arow = wr * 64 + l31;
    const int brow = wc * 64 + l31;
    const int NT = Kc >> 5;

    f32x16 acc[2][2] = {};  // [rb][cb] 32x32 tiles

    auto STAGE = [&](const int buf, const int kt) {
        const int ko = kt * 32;
        load_lds16(srcA0 + ko, &As[buf][tid * 8]);
        load_lds16(srcA1 + ko, &As[buf][(tid + 256) * 8]);
        load_lds16(srcB0 + ko, &Bs[buf][tid * 8]);
        load_lds16(srcB1 + ko, &Bs[buf][(tid + 256) * 8]);
    };

    // prologue: tile 0 into buf 0
    STAGE(0, 0);
    __syncthreads();  // vmcnt(0) drained at barrier -> buf0 visible

    for (int t = 0; t < NT; ++t) {
        const int cur = t & 1;
        if (t + 1 < NT) STAGE(cur ^ 1, t + 1);  // prefetch next tile (other buf)

        f16x8 a[2][2], b[2][2];  // [rb/cb][kh]
#pragma unroll
        for (int rb = 0; rb < 2; ++rb)
#pragma unroll
            for (int kh = 0; kh < 2; ++kh)
                a[rb][kh] = *(const f16x8*)&As[cur][(arow + rb * 32) * 32 +
                                                   (((2 * kh + hi) ^ nsw) * 8)];
#pragma unroll
        for (int cb = 0; cb < 2; ++cb)
#pragma unroll
            for (int kh = 0; kh < 2; ++kh)
                b[cb][kh] = *(const f16x8*)&Bs[cur][(brow + cb * 32) * 32 +
                                                   (((2 * kh + hi) ^ nsw) * 8)];
#pragma unroll
        for (int rb = 0; rb < 2; ++rb)
#pragma unroll
            for (int cb = 0; cb < 2; ++cb) {
                acc[rb][cb] = __builtin_amdgcn_mfma_f32_32x32x16_f16(
                    a[rb][0], b[cb][0], acc[rb][cb], 0, 0, 0);
                acc[rb][cb] = __builtin_amdgcn_mfma_f32_32x32x16_f16(
                    a[rb][1], b[cb][1], acc[rb][cb], 0, 0, 0);
            }

        __syncthreads();  // vmcnt(0)+lgkmcnt(0): next tile landed, cur reads done
    }

    // epilogue: C/D (m74/m101): col = lane&31, row = (q&3) + 8*(q>>2) + 4*hi
#pragma unroll
    for (int rb = 0; rb < 2; ++rb)
#pragma unroll
        for (int cb = 0; cb < 2; ++cb) {
            const int colb = n0 + wc * 64 + cb * 32 + l31;
            const int rowb = m0 + wr * 64 + rb * 32 + 4 * hi;
#pragma unroll
            for (int q = 0; q < 16; ++q) {
                const int row = rowb + (q & 3) + 8 * (q >> 2);
                if (OBF) {
                    ((ushort*)Cp)[(size_t)row * ldc + colb] = f_to_f16(acc[rb][cb][q]);
                } else {
                    ((float*)Cp)[(size_t)row * ldc + colb] = acc[rb][cb][q];
                }
            }
        }
}

// ---------------------------------------------------------------------------
// conv + gate on fp16 qkv [B,L,3072]; writes gated fp16 [B,L,1024].
// decay geometric => exact IIR for the 128-tap FIR:
//   res[l] = r*res[l-1] + src[l] - decay128*src[l-128],  src = k*v (fp32 state)
// LCHUNK=128 (was 64): halves the seed-tap re-read traffic (~66MB saved).
// ---------------------------------------------------------------------------
__global__ __launch_bounds__(256) void conv_gate_f16(const ushort* __restrict__ qkvh,
                                                     const float* __restrict__ decay,
                                                     ushort* __restrict__ gh) {
    __shared__ float sdec[KTAPS];
    if (threadIdx.x < KTAPS) sdec[threadIdx.x] = decay[threadIdx.x];
    __syncthreads();

    const int d = blockIdx.y * 256 + threadIdx.x;
    const int b = blockIdx.z;
    const int l0 = blockIdx.x * LCHUNK;

    const float r = sdec[1];
    const float dlast = r * sdec[KTAPS - 1];  // decay[128]
    const size_t rs = 3 * DDIM;

    const ushort* base = qkvh + (size_t)b * LDIM * rs;
    const ushort* qc = base + d;
    const ushort* kc = base + DDIM + d;
    const ushort* vc = base + 2 * DDIM + d;
    ushort* g0 = gh + (size_t)b * LDIM * DDIM + d;

    float res = 0.f;
    int lstart;
    if (l0 == 0) {
        lstart = 0;
    } else {
        const int tmax = (l0 < KTAPS - 1) ? l0 : (KTAPS - 1);
#pragma unroll 4
        for (int t = 0; t <= tmax; ++t) {
            const size_t off = (size_t)(l0 - t) * rs;
            res += sdec[t] * f16_to_f(kc[off]) * f16_to_f(vc[off]);
        }
        g0[(size_t)l0 * DDIM] = f_to_f16(f16_to_f(qc[(size_t)l0 * rs]) * res);
        lstart = l0 + 1;
    }

    for (int l = lstart; l < l0 + LCHUNK; ++l) {
        const size_t off = (size_t)l * rs;
        const float s = f16_to_f(kc[off]) * f16_to_f(vc[off]);
        if (l == 0) {
            res = sdec[0] * s;
        } else {
            float sub = 0.f;
            if (l >= KTAPS) {
                const size_t o2 = (size_t)(l - KTAPS) * rs;
                sub = dlast * f16_to_f(kc[o2]) * f16_to_f(vc[o2]);
            }
            res = r * res + s - sub;
        }
        g0[(size_t)l * DDIM] = f_to_f16(f16_to_f(qc[off]) * res);
    }
}

// ---------------------------------------------------------------------------
// Memory plan (ws proven >= 192MB; uses 168MB):
//   ws[  0.. 96MB) qkvh  f16 [16384,3072]  GEMM1 out
//   ws[ 96..128MB) gh    f16 [16384,1024]  conv out = GEMM2 A
//   ws[128..160MB) xh    f16 [16384,1024]  GEMM1 A
//   ws[160..166MB) wqkvh f16 [3072,1024]   GEMM1 B
//   ws[166..168MB) wouth f16 [1024,1024]   GEMM2 B
// ---------------------------------------------------------------------------
extern "C" void kernel_launch(void* const* d_in, const int* in_sizes, int n_in,
                              void* d_out, int out_size, void* d_ws, size_t ws_size,
                              hipStream_t stream) {
    const float* x = (const float*)d_in[0];
    const float* Wqkv = (const float*)d_in[1];
    const float* Wout = (const float*)d_in[2];
    const float* decay = (const float*)d_in[3];

    const int M = BDIM * LDIM;  // 16384
    const size_t MB = 1024 * 1024;

    ushort* qkvh = (ushort*)d_ws;
    ushort* gh = (ushort*)((char*)d_ws + 96 * MB);
    ushort* xh = (ushort*)((char*)d_ws + 128 * MB);
    ushort* wqkvh = (ushort*)((char*)d_ws + 160 * MB);
    ushort* wouth = (ushort*)((char*)d_ws + 166 * MB);

    // all three converts in one launch
    to_f16_all<<<2048, 256, 0, stream>>>(x, Wqkv, Wout, xh, wqkvh, wouth);

    // GEMM1: qkvh = xh @ wqkvh^T  [16384,1024]x[3072,1024]^T, f16 out
    dim3 g1(3 * DDIM / 128, M / 128);  // 24 x 128 = 3072 wgs (%8==0)
    gemm_f16<1><<<g1, 256, 0, stream>>>(xh, wqkvh, qkvh, 3 * DDIM, DDIM);

    // conv + gate -> gh
    dim3 g2(LDIM / LCHUNK, DDIM / 256, BDIM);  // 32 x 4 x 4 = 512 blocks
    conv_gate_f16<<<g2, 256, 0, stream>>>(qkvh, decay, gh);

    // GEMM2: out = gh @ wouth^T  [16384,1024]x[1024,1024]^T, f32 out
    dim3 g3(DDIM / 128, M / 128);  // 8 x 128 = 1024 wgs (%8==0)
    gemm_f16<0><<<g3, 256, 0, stream>>>(gh, wouth, d_out, DDIM, DDIM);
}

// Round 10
// 296.196 us; speedup vs baseline: 1.1238x; 1.1238x over previous
//
#include <hip/hip_runtime.h>

#define BDIM 4
#define LDIM 4096
#define DDIM 1024
#define KTAPS 128
#define LCHUNK 64

typedef __attribute__((ext_vector_type(8))) _Float16 f16x8;
typedef __attribute__((ext_vector_type(16))) float f32x16;

// ---------------------------------------------------------------------------
// fp16 helpers
// ---------------------------------------------------------------------------
__device__ __forceinline__ float f16_to_f(ushort h) {
    return (float)__builtin_bit_cast(_Float16, h);
}
__device__ __forceinline__ ushort f_to_f16(float f) {
    return __builtin_bit_cast(ushort, (_Float16)f);  // v_cvt_f16_f32, RNE
}

__device__ __forceinline__ void load_lds16(const ushort* g, ushort* l) {
    __builtin_amdgcn_global_load_lds(
        (const __attribute__((address_space(1))) void*)g,
        (__attribute__((address_space(3))) void*)l, 16, 0, 0);
}

// granule swizzle for LDS row r (4 octets of 16B per 64B row); period-16 in r
#define NSWZ(r) ((((r) & 3) ^ (((r) >> 2) & 3)))

// ---------------------------------------------------------------------------
// fused fp32 -> fp16 convert for all three inputs (one launch)
// ---------------------------------------------------------------------------
#define NX4 (BDIM * LDIM * DDIM / 4)        // 4194304
#define NQ4 (3 * DDIM * DDIM / 4)           // 786432
#define NO4 (DDIM * DDIM / 4)               // 262144
__global__ __launch_bounds__(256) void to_f16_all(const float* __restrict__ x,
                                                  const float* __restrict__ wq,
                                                  const float* __restrict__ wo,
                                                  ushort* __restrict__ xh,
                                                  ushort* __restrict__ wqh,
                                                  ushort* __restrict__ woh) {
    const int ntot = NX4 + NQ4 + NO4;
    for (int i = blockIdx.x * 256 + threadIdx.x; i < ntot; i += gridDim.x * 256) {
        const float* src;
        ushort* dst;
        int j = i;
        if (j < NX4) {
            src = x; dst = xh;
        } else if (j < NX4 + NQ4) {
            j -= NX4; src = wq; dst = wqh;
        } else {
            j -= NX4 + NQ4; src = wo; dst = woh;
        }
        const float4 v = *(const float4*)&src[(size_t)j * 4];
        ushort4 h;
        h.x = f_to_f16(v.x);
        h.y = f_to_f16(v.y);
        h.z = f_to_f16(v.z);
        h.w = f_to_f16(v.w);
        *(ushort4*)&dst[(size_t)j * 4] = h;
    }
}

// ---------------------------------------------------------------------------
// fp16 NT GEMM: 128x128 tile, BK=32, 4 waves, 32x32x16 MFMA.
// ROUND-10 CHANGE: T4 counted-vmcnt DEEP pipeline — 3-buffer LDS ring with
// TWO tiles in flight. Iter t: issue STAGE(t+2), compute buf t%3, then
// s_waitcnt vmcnt(4) (t+2's loads stay outstanding; t+1's have landed) +
// raw s_barrier. Look-ahead distance = 2 iterations (~580+ cyc) >= L2/HBM
// latency; round-9's 1-ahead + drain-0 exposed ~290 cyc every iter.
// Ring hazard: STAGE(t) overwrites the buffer read at iter t-1, whose
// ds_reads completed before the iter-(t-1) barrier (compiler lgkm waits
// precede the MFMAs that consume them). LDS = 3 x 16KB = 48KB -> 3 blk/CU.
// A/B frag map: lane l -> row/col = l&31, k-octet = l>>5;
// C/D map (m74/m101): col = lane&31, row = (q&3)+8*(q>>2)+4*(lane>>5).
// OBF=1 -> f16 C, OBF=0 -> f32 C. XCD-aware tile swizzle.
// ---------------------------------------------------------------------------
template <int OBF>
__global__ __launch_bounds__(256) void gemm_f16(const ushort* __restrict__ A,
                                                const ushort* __restrict__ B,
                                                void* __restrict__ Cp, int ldc, int Kc) {
    __shared__ ushort As[3][128 * 32];
    __shared__ ushort Bs[3][128 * 32];

    const int tid = threadIdx.x;

    // bijective XCD swizzle (nwg % 8 == 0 for all our grids)
    const int gx = gridDim.x;
    const int nwg = gx * gridDim.y;
    const int orig = blockIdx.y * gx + blockIdx.x;
    const int q8 = nwg >> 3;
    const int tile = (orig & 7) * q8 + (orig >> 3);
    const int m0 = (tile / gx) * 128;
    const int n0 = (tile % gx) * 128;

    // staging: thread t -> LDS rows t>>2 and t>>2 + 64, octet t&3; inverse-swizzled src
    const int ra = tid >> 2;
    const int ga = tid & 3;
    const int gs = (ga ^ NSWZ(ra)) * 8;

    const ushort* srcA0 = A + (size_t)(m0 + ra) * Kc + gs;
    const ushort* srcA1 = A + (size_t)(m0 + 64 + ra) * Kc + gs;
    const ushort* srcB0 = B + (size_t)(n0 + ra) * Kc + gs;
    const ushort* srcB1 = B + (size_t)(n0 + 64 + ra) * Kc + gs;

    const int lane = tid & 63;
    const int w = tid >> 6;
    const int wr = w >> 1, wc = w & 1;  // wave 64x64 sub-tile
    const int l31 = lane & 31;
    const int hi = lane >> 5;           // k-octet half (A/B), +4 row offset (C/D)
    const int nsw = NSWZ(l31 & 15);
    const int arow = wr * 64 + l31;
    const int brow = wc * 64 + l31;
    const int NT = Kc >> 5;

    f32x16 acc[2][2] = {};  // [rb][cb] 32x32 tiles

    auto STAGE = [&](const int buf, const int kt) {
        const int ko = kt * 32;
        load_lds16(srcA0 + ko, &As[buf][tid * 8]);
        load_lds16(srcA1 + ko, &As[buf][(tid + 256) * 8]);
        load_lds16(srcB0 + ko, &Bs[buf][tid * 8]);
        load_lds16(srcB1 + ko, &Bs[buf][(tid + 256) * 8]);
    };

    // prologue: tiles 0,1 into bufs 0,1; ensure tile 0 landed (4 newer remain)
    STAGE(0, 0);
    if (NT > 1) {
        STAGE(1, 1);
        asm volatile("s_waitcnt vmcnt(4)" ::: "memory");
    } else {
        asm volatile("s_waitcnt vmcnt(0)" ::: "memory");
    }
    __builtin_amdgcn_s_barrier();

    int cur = 0;
    for (int t = 0; t < NT; ++t) {
        const int nx2 = (cur + 2 >= 3) ? cur - 1 : cur + 2;  // (t+2)%3
        if (t + 2 < NT) STAGE(nx2, t + 2);

        f16x8 a[2][2], b[2][2];  // [rb/cb][kh]
#pragma unroll
        for (int rb = 0; rb < 2; ++rb)
#pragma unroll
            for (int kh = 0; kh < 2; ++kh)
                a[rb][kh] = *(const f16x8*)&As[cur][(arow + rb * 32) * 32 +
                                                   (((2 * kh + hi) ^ nsw) * 8)];
#pragma unroll
        for (int cb = 0; cb < 2; ++cb)
#pragma unroll
            for (int kh = 0; kh < 2; ++kh)
                b[cb][kh] = *(const f16x8*)&Bs[cur][(brow + cb * 32) * 32 +
                                                   (((2 * kh + hi) ^ nsw) * 8)];
#pragma unroll
        for (int rb = 0; rb < 2; ++rb)
#pragma unroll
            for (int cb = 0; cb < 2; ++cb) {
                acc[rb][cb] = __builtin_amdgcn_mfma_f32_32x32x16_f16(
                    a[rb][0], b[cb][0], acc[rb][cb], 0, 0, 0);
                acc[rb][cb] = __builtin_amdgcn_mfma_f32_32x32x16_f16(
                    a[rb][1], b[cb][1], acc[rb][cb], 0, 0, 0);
            }

        // tile t+1 must be landed before next iter reads it; t+2 stays in flight
        if (t + 2 < NT) {
            asm volatile("s_waitcnt vmcnt(4)" ::: "memory");
        } else if (t + 1 < NT) {
            asm volatile("s_waitcnt vmcnt(0)" ::: "memory");
        }
        __builtin_amdgcn_s_barrier();
        cur = (cur + 1 >= 3) ? 0 : cur + 1;
    }

    // epilogue: C/D (m74/m101): col = lane&31, row = (q&3) + 8*(q>>2) + 4*hi
#pragma unroll
    for (int rb = 0; rb < 2; ++rb)
#pragma unroll
        for (int cb = 0; cb < 2; ++cb) {
            const int colb = n0 + wc * 64 + cb * 32 + l31;
            const int rowb = m0 + wr * 64 + rb * 32 + 4 * hi;
#pragma unroll
            for (int q = 0; q < 16; ++q) {
                const int row = rowb + (q & 3) + 8 * (q >> 2);
                if (OBF) {
                    ((ushort*)Cp)[(size_t)row * ldc + colb] = f_to_f16(acc[rb][cb][q]);
                } else {
                    ((float*)Cp)[(size_t)row * ldc + colb] = acc[rb][cb][q];
                }
            }
        }
}

// ---------------------------------------------------------------------------
// conv + gate on fp16 qkv [B,L,3072]; writes gated fp16 [B,L,1024].
// decay geometric => exact IIR for the 128-tap FIR:
//   res[l] = r*res[l-1] + src[l] - decay128*src[l-128],  src = k*v (fp32 state)
// LCHUNK=64 (r9's 128 regressed ~48us: conv is serial-latency-bound, more
// blocks with shorter chains win).
// ---------------------------------------------------------------------------
__global__ __launch_bounds__(256) void conv_gate_f16(const ushort* __restrict__ qkvh,
                                                     const float* __restrict__ decay,
                                                     ushort* __restrict__ gh) {
    __shared__ float sdec[KTAPS];
    if (threadIdx.x < KTAPS) sdec[threadIdx.x] = decay[threadIdx.x];
    __syncthreads();

    const int d = blockIdx.y * 256 + threadIdx.x;
    const int b = blockIdx.z;
    const int l0 = blockIdx.x * LCHUNK;

    const float r = sdec[1];
    const float dlast = r * sdec[KTAPS - 1];  // decay[128]
    const size_t rs = 3 * DDIM;

    const ushort* base = qkvh + (size_t)b * LDIM * rs;
    const ushort* qc = base + d;
    const ushort* kc = base + DDIM + d;
    const ushort* vc = base + 2 * DDIM + d;
    ushort* g0 = gh + (size_t)b * LDIM * DDIM + d;

    float res = 0.f;
    int lstart;
    if (l0 == 0) {
        lstart = 0;
    } else {
        const int tmax = (l0 < KTAPS - 1) ? l0 : (KTAPS - 1);
#pragma unroll 4
        for (int t = 0; t <= tmax; ++t) {
            const size_t off = (size_t)(l0 - t) * rs;
            res += sdec[t] * f16_to_f(kc[off]) * f16_to_f(vc[off]);
        }
        g0[(size_t)l0 * DDIM] = f_to_f16(f16_to_f(qc[(size_t)l0 * rs]) * res);
        lstart = l0 + 1;
    }

    for (int l = lstart; l < l0 + LCHUNK; ++l) {
        const size_t off = (size_t)l * rs;
        const float s = f16_to_f(kc[off]) * f16_to_f(vc[off]);
        if (l == 0) {
            res = sdec[0] * s;
        } else {
            float sub = 0.f;
            if (l >= KTAPS) {
                const size_t o2 = (size_t)(l - KTAPS) * rs;
                sub = dlast * f16_to_f(kc[o2]) * f16_to_f(vc[o2]);
            }
            res = r * res + s - sub;
        }
        g0[(size_t)l * DDIM] = f_to_f16(f16_to_f(qc[off]) * res);
    }
}

// ---------------------------------------------------------------------------
// Memory plan (ws proven >= 192MB; uses 168MB):
//   ws[  0.. 96MB) qkvh  f16 [16384,3072]  GEMM1 out
//   ws[ 96..128MB) gh    f16 [16384,1024]  conv out = GEMM2 A
//   ws[128..160MB) xh    f16 [16384,1024]  GEMM1 A
//   ws[160..166MB) wqkvh f16 [3072,1024]   GEMM1 B
//   ws[166..168MB) wouth f16 [1024,1024]   GEMM2 B
// ---------------------------------------------------------------------------
extern "C" void kernel_launch(void* const* d_in, const int* in_sizes, int n_in,
                              void* d_out, int out_size, void* d_ws, size_t ws_size,
                              hipStream_t stream) {
    const float* x = (const float*)d_in[0];
    const float* Wqkv = (const float*)d_in[1];
    const float* Wout = (const float*)d_in[2];
    const float* decay = (const float*)d_in[3];

    const int M = BDIM * LDIM;  // 16384
    const size_t MB = 1024 * 1024;

    ushort* qkvh = (ushort*)d_ws;
    ushort* gh = (ushort*)((char*)d_ws + 96 * MB);
    ushort* xh = (ushort*)((char*)d_ws + 128 * MB);
    ushort* wqkvh = (ushort*)((char*)d_ws + 160 * MB);
    ushort* wouth = (ushort*)((char*)d_ws + 166 * MB);

    // all three converts in one launch
    to_f16_all<<<2048, 256, 0, stream>>>(x, Wqkv, Wout, xh, wqkvh, wouth);

    // GEMM1: qkvh = xh @ wqkvh^T  [16384,1024]x[3072,1024]^T, f16 out
    dim3 g1(3 * DDIM / 128, M / 128);  // 24 x 128 = 3072 wgs (%8==0)
    gemm_f16<1><<<g1, 256, 0, stream>>>(xh, wqkvh, qkvh, 3 * DDIM, DDIM);

    // conv + gate -> gh
    dim3 g2(LDIM / LCHUNK, DDIM / 256, BDIM);  // 64 x 4 x 4 = 1024 blocks
    conv_gate_f16<<<g2, 256, 0, stream>>>(qkvh, decay, gh);

    // GEMM2: out = gh @ wouth^T  [16384,1024]x[1024,1024]^T, f32 out
    dim3 g3(DDIM / 128, M / 128);  // 8 x 128 = 1024 wgs (%8==0)
    gemm_f16<0><<<g3, 256, 0, stream>>>(gh, wouth, d_out, DDIM, DDIM);
}